// Round 22
// baseline (64.874 us; speedup 1.0000x reference)
//
#include <hip/hip_runtime.h>
#include <math.h>

#define NE 8
#define PI_F 3.14159265358979323846f

typedef _Float16 half8 __attribute__((ext_vector_type(8)));
typedef float f32x4 __attribute__((ext_vector_type(4)));
typedef float f32x16 __attribute__((ext_vector_type(16)));
typedef unsigned int uint2v __attribute__((ext_vector_type(2)));
typedef unsigned int u32x4 __attribute__((ext_vector_type(4)));
typedef unsigned short u16x4 __attribute__((ext_vector_type(4)));

// Activation LDS layout: fp16, [y 0..9][x 0..9][c 0..23(pad)], u16 units
#define CP 24
#define ROWS 240        // 10 * CP
#define NELEM 2400      // 10*10*CP u16

__device__ __forceinline__ unsigned short f2h_bits(float v) {
    union { _Float16 h; unsigned short u; } cv;
    cv.h = (_Float16)v;
    return cv.u;
}

// ---------------- Setup: routers (blocks 0..255) + weight prep --------------
struct SetupArgs {
    const float* rw[4]; const float* rb[4]; const float* rlw[4]; const float* rlb[4];
    const float* ew[4];
    float* probs;
    unsigned short* w0; unsigned short* w1; unsigned short* w2; unsigned short* w3;
};

// 32x32x16 A-fragment prep. k = r*CSTR + cin. m indexes ew rows directly.
// Fragment (mt,ks,lane,j): m = mt*32 + (lane&31), k = ks*16 + (lane>>5)*8 + j.
template<int CIN, int CSTR, int KSL>
__device__ __forceinline__ void prep_one32(
    const float* __restrict__ ew, unsigned short* __restrict__ wA, int idx)
{
    int j    = idx & 7;
    int lane = (idx >> 3) & 63;
    int t2   = idx >> 9;
    int ks   = t2 % KSL;
    int mt   = t2 / KSL;
    int m    = mt * 32 + (lane & 31);
    int k    = ks * 16 + (lane >> 5) * 8 + j;
    int cin  = k % CSTR, r = k / CSTR;
    float val = 0.0f;
    if (cin < CIN && r < 9)
        val = ew[((size_t)m * CIN + cin) * 9 + r];
    wA[idx] = f2h_bits(val);
}

__global__ __launch_bounds__(256) void setup_all(SetupArgs sa)
{
    int bx = blockIdx.x, tid = threadIdx.x;
    if (bx < 256) {
        int layer = tid >> 6, lane = tid & 63;
        const float* rw  = sa.rw[layer];  const float* rb  = sa.rb[layer];
        const float* rlw = sa.rlw[layer]; const float* rlb = sa.rlb[layer];
        int p = bx, py = p >> 4, px = p & 15;
        int i = lane >> 3, j = lane & 7;
        int y = py * 8 + i, x = px * 8 + j;

        float base0 = (x + 0.5f) / 128.0f;
        float base1 = (y + 0.5f) / 128.0f;
        float base2 = (j + 0.5f) / 8.0f;
        float base3 = (i + 0.5f) / 8.0f;

        float coord[52];
        coord[0] = base0; coord[1] = base1; coord[2] = base2; coord[3] = base3;
        int c = 4;
        #pragma unroll
        for (int f = 0; f < 6; ++f) {
            float w = PI_F * (float)(1 << f);
            coord[c+0] = sinf(w * base0); coord[c+1] = sinf(w * base1);
            coord[c+2] = sinf(w * base2); coord[c+3] = sinf(w * base3);
            coord[c+4] = cosf(w * base0); coord[c+5] = cosf(w * base1);
            coord[c+6] = cosf(w * base2); coord[c+7] = cosf(w * base3);
            c += 8;
        }
        float z[16];
        #pragma unroll
        for (int r = 0; r < 16; ++r) {
            float a = rb[r];
            #pragma unroll
            for (int cc = 0; cc < 52; ++cc) a += rw[r*52 + cc] * coord[cc];
            z[r] = fmaxf(a, 0.0f);
        }
        #pragma unroll
        for (int r = 0; r < 16; ++r) {
            float v = z[r];
            #pragma unroll
            for (int off = 32; off > 0; off >>= 1) v += __shfl_xor(v, off);
            z[r] = v * (1.0f / 64.0f);
        }
        int e = lane & 7;
        float logit = rlb[e];
        #pragma unroll
        for (int r = 0; r < 16; ++r) logit += rlw[e*16 + r] * z[r];
        float m = logit;
        #pragma unroll
        for (int off = 4; off > 0; off >>= 1) m = fmaxf(m, __shfl_xor(m, off));
        float ex = expf(logit - m);
        float s = ex;
        #pragma unroll
        for (int off = 4; off > 0; off >>= 1) s += __shfl_xor(s, off);
        float pr = ex / s;
        pr = (pr >= 0.05f) ? pr : 0.0f;
        float s2 = pr;
        #pragma unroll
        for (int off = 4; off > 0; off >>= 1) s2 += __shfl_xor(s2, off);
        pr = pr / (s2 + 1e-9f);
        if (lane < 8) sa.probs[layer * 2048 + p * 8 + lane] = pr;
    } else {
        int idx = (bx - 256) * 256 + tid;
        if (idx < 3072)       prep_one32<3, 4, 3>(sa.ew[0], sa.w0, idx);
        else if (idx < 13312) prep_one32<8, 8, 5>(sa.ew[1], sa.w1, idx - 3072);
        else if (idx < 31744) prep_one32<16, 16, 9>(sa.ew[2], sa.w2, idx - 13312);
        else if (idx < 68608) prep_one32<16, 16, 9>(sa.ew[3], sa.w3, idx - 31744);
    }
}

// ---------------- B-fragment build: pixel n (0..63), channel-half hi --------
template<int KSL, int CSTR>
__device__ __forceinline__ void build_B32(
    half8* B, const unsigned short* ain, int n, int hi)
{
    int pr = n >> 3, pc = n & 7;
    int rbase = pr * ROWS + pc * CP;
    if (CSTR == 16) {
        #pragma unroll
        for (int ks = 0; ks < KSL; ++ks) {
            int off = ((ks / 3) * 10 + (ks % 3)) * CP + hi * 8;
            B[ks] = *(const half8*)(ain + rbase + off);
        }
    } else if (CSTR == 8) {
        #pragma unroll
        for (int ks = 0; ks < KSL; ++ks) {
            int r0 = 2 * ks, r1 = 2 * ks + 1;
            int o0 = ((r0 / 3) * 10 + (r0 % 3)) * CP;
            int o1 = (r1 < 9) ? ((r1 / 3) * 10 + (r1 % 3)) * CP : 0;
            int off = hi ? o1 : o0;
            half8 v{};
            if (2 * ks + hi < 9) v = *(const half8*)(ain + rbase + off);
            B[ks] = v;
        }
    } else { // CSTR == 4
        #pragma unroll
        for (int ks = 0; ks < KSL; ++ks) {
            union { half8 v; uint2v u2[2]; } bb;
            #pragma unroll
            for (int h = 0; h < 2; ++h) {
                int ra = 4 * ks + h;          // hi=0 taps
                int rb_ = 4 * ks + 2 + h;     // hi=1 taps
                int oa = (ra < 9) ? ((ra / 3) * 10 + (ra % 3)) * CP : 0;
                int ob = (rb_ < 9) ? ((rb_ / 3) * 10 + (rb_ % 3)) * CP : 0;
                int r = 4 * ks + 2 * hi + h;
                int off = hi ? ob : oa;
                uint2v u{};
                if (r < 9) u = *(const uint2v*)(ain + rbase + off);
                bb.u2[h] = u;
            }
            B[ks] = bb.v;
        }
    }
}

// ---------------- One layer, 32x32x16 MFMA, whole patch per wave ------------
// CPE = channels per expert (8, 16, 32). sbR_L = bias in C-reg order.
// s_setprio(1) wraps the MFMA cluster (T5, verified +17% in R20).
// mtile loop at unroll 2: lets mt's epilogue VALU interleave under mt+1's
// MFMA issue (bubble removal; spill tripwire = WRITE_SIZE).
template<int KSL, int CSTR, int MT, int CPE, bool LAST>
__device__ __forceinline__ void layer32(
    unsigned short* Aw,
    const unsigned short* __restrict__ wA,
    const float* sbR_L, const float* se_L,
    int l, int hi, int l31, float* pout)
{
    int n0 = l31, n1 = 32 + l31;
    half8 B0[KSL], B1[KSL];
    build_B32<KSL, CSTR>(B0, Aw, n0, hi);
    build_B32<KSL, CSTR>(B1, Aw, n1, hi);

    constexpr int KH0 = (KSL + 1) / 2;
    constexpr int KH1 = KSL - KH0;

    f32x16 accL = {0.f};                         // CPE==32 (LAST)
    f32x4 acc0a = {0,0,0,0}, acc0b = {0,0,0,0};  // CPE==16 nt0
    f32x4 acc1a = {0,0,0,0}, acc1b = {0,0,0,0};  // CPE==16 nt1
    f32x4 acc0s = {0,0,0,0}, acc1s = {0,0,0,0};  // CPE==8

    const unsigned short* apl = wA + l * 8;
    half8 A0[KH0], A1[KH1 > 0 ? KH1 : 1];
    #pragma unroll
    for (int q = 0; q < KH0; ++q)
        A0[q] = *(const half8*)(apl + q * 512);

    #pragma unroll 2
    for (int mt = 0; mt < MT; ++mt) {
        const unsigned short* base = apl + mt * (KSL * 512);
        #pragma unroll
        for (int q = 0; q < KH1; ++q)
            A1[q] = *(const half8*)(base + (KH0 + q) * 512);

        const float* bp = sbR_L + mt * 32 + hi * 16;
        f32x4 b0 = *(const f32x4*)(bp);
        f32x4 b1 = *(const f32x4*)(bp + 4);
        f32x4 b2 = *(const f32x4*)(bp + 8);
        f32x4 b3 = *(const f32x4*)(bp + 12);
        f32x16 ct0;
        #pragma unroll
        for (int i = 0; i < 4; ++i) {
            ct0[i] = b0[i]; ct0[4+i] = b1[i]; ct0[8+i] = b2[i]; ct0[12+i] = b3[i];
        }
        f32x16 ct1 = ct0;

        __builtin_amdgcn_s_setprio(1);
        #pragma unroll
        for (int q = 0; q < KH0; ++q) {
            ct0 = __builtin_amdgcn_mfma_f32_32x32x16_f16(A0[q], B0[q], ct0, 0, 0, 0);
            ct1 = __builtin_amdgcn_mfma_f32_32x32x16_f16(A0[q], B1[q], ct1, 0, 0, 0);
        }

        const unsigned short* nbase = apl + ((mt + 1 < MT) ? (mt + 1) : 0) * (KSL * 512);
        #pragma unroll
        for (int q = 0; q < KH0; ++q)
            A0[q] = *(const half8*)(nbase + q * 512);

        #pragma unroll
        for (int q = 0; q < KH1; ++q) {
            ct0 = __builtin_amdgcn_mfma_f32_32x32x16_f16(A1[q], B0[KH0 + q], ct0, 0, 0, 0);
            ct1 = __builtin_amdgcn_mfma_f32_32x32x16_f16(A1[q], B1[KH0 + q], ct1, 0, 0, 0);
        }
        __builtin_amdgcn_s_setprio(0);

        if (CPE == 32) {
            float pe = se_L[mt];
            #pragma unroll
            for (int g = 0; g < 16; ++g)
                accL[g] = fmaf(fmaxf(ct0[g], 0.f) + fmaxf(ct1[g], 0.f), pe, accL[g]);
        } else if (CPE == 16) {
            float pe0 = se_L[2 * mt], pe1 = se_L[2 * mt + 1];
            #pragma unroll
            for (int g = 0; g < 4; ++g) {
                acc0a[g] = fmaf(fmaxf(ct0[g],      0.f), pe0, acc0a[g]);
                acc0a[g] = fmaf(fmaxf(ct0[8 + g],  0.f), pe1, acc0a[g]);
                acc0b[g] = fmaf(fmaxf(ct0[4 + g],  0.f), pe0, acc0b[g]);
                acc0b[g] = fmaf(fmaxf(ct0[12 + g], 0.f), pe1, acc0b[g]);
                acc1a[g] = fmaf(fmaxf(ct1[g],      0.f), pe0, acc1a[g]);
                acc1a[g] = fmaf(fmaxf(ct1[8 + g],  0.f), pe1, acc1a[g]);
                acc1b[g] = fmaf(fmaxf(ct1[4 + g],  0.f), pe0, acc1b[g]);
                acc1b[g] = fmaf(fmaxf(ct1[12 + g], 0.f), pe1, acc1b[g]);
            }
        } else { // CPE == 8
            #pragma unroll
            for (int q = 0; q < 4; ++q) {
                float pe = se_L[4 * mt + q];
                #pragma unroll
                for (int g = 0; g < 4; ++g) {
                    acc0s[g] = fmaf(fmaxf(ct0[4 * q + g], 0.f), pe, acc0s[g]);
                    acc1s[g] = fmaf(fmaxf(ct1[4 * q + g], 0.f), pe, acc1s[g]);
                }
            }
        }
    }

    if (!LAST) {
        int wb0 = (1 + (n0 >> 3)) * ROWS + (1 + (n0 & 7)) * CP;
        int wb1 = (1 + (n1 >> 3)) * ROWS + (1 + (n1 & 7)) * CP;
        union { _Float16 h[4]; u16x4 u; } o;
        if (CPE == 8) {
            #pragma unroll
            for (int g = 0; g < 4; ++g) o.h[g] = (_Float16)acc0s[g];
            *(u16x4*)(Aw + wb0 + 4 * hi) = o.u;
            #pragma unroll
            for (int g = 0; g < 4; ++g) o.h[g] = (_Float16)acc1s[g];
            *(u16x4*)(Aw + wb1 + 4 * hi) = o.u;
        } else { // CPE == 16
            #pragma unroll
            for (int g = 0; g < 4; ++g) o.h[g] = (_Float16)acc0a[g];
            *(u16x4*)(Aw + wb0 + 4 * hi) = o.u;
            #pragma unroll
            for (int g = 0; g < 4; ++g) o.h[g] = (_Float16)acc0b[g];
            *(u16x4*)(Aw + wb0 + 8 + 4 * hi) = o.u;
            #pragma unroll
            for (int g = 0; g < 4; ++g) o.h[g] = (_Float16)acc1a[g];
            *(u16x4*)(Aw + wb1 + 4 * hi) = o.u;
            #pragma unroll
            for (int g = 0; g < 4; ++g) o.h[g] = (_Float16)acc1b[g];
            *(u16x4*)(Aw + wb1 + 8 + 4 * hi) = o.u;
        }
    } else {
        // channel sums over 64 pixels: xor-reduce within 32-lane halves
        #pragma unroll
        for (int g = 0; g < 16; ++g) {
            float s = accL[g];
            s += __shfl_xor(s, 1);  s += __shfl_xor(s, 2);
            s += __shfl_xor(s, 4);  s += __shfl_xor(s, 8);
            s += __shfl_xor(s, 16);
            accL[g] = s;
        }
        if (l31 == 0) {
            #pragma unroll
            for (int qd = 0; qd < 4; ++qd) {
                f32x4 v = { accL[4*qd], accL[4*qd+1], accL[4*qd+2], accL[4*qd+3] };
                *(f32x4*)(pout + qd * 8 + 4 * hi) = v;
            }
        }
    }
}

// ---------------- Fused all-4-layer conv, 1 patch per wave, 32x32 MFMA ------
__global__ __launch_bounds__(256, 2) void pce_fused(
    const float* __restrict__ X,
    const unsigned short* __restrict__ wA0, const unsigned short* __restrict__ wA1,
    const unsigned short* __restrict__ wA2, const unsigned short* __restrict__ wA3,
    const float* __restrict__ eb0, const float* __restrict__ eb1,
    const float* __restrict__ eb2, const float* __restrict__ eb3,
    const float* __restrict__ probs,  // [4][256][8]
    float* __restrict__ psums)        // [16][256][32]
{
    int bx = blockIdx.x;              // 0..1023
    int b = bx >> 6;
    int pbase = (bx & 63) << 2;
    int tid = threadIdx.x;
    int w = tid >> 6, l = tid & 63;
    int p = pbase + w;
    int py = p >> 4, px = p & 15;

    __shared__ alignas(16) unsigned short A[4][NELEM];   // 19.2 KB
    __shared__ alignas(16) float sbR[576];               // bias, C-reg order
    __shared__ alignas(16) float se[4][4][8];            // [layer][wave][expert]

    if (tid < 128) {
        int layer = tid >> 5, q = (tid >> 3) & 3, e = tid & 7;
        se[layer][q][e] = probs[layer * 2048 + (pbase + q) * 8 + e];
    }
    // bias reorder: sbR[off + mt*32 + hi*16 + reg] = ebL[mt*32 + row(reg,hi)]
    for (int t = tid; t < 576; t += 256) {
        const float* ebp; int off;
        if (t < 64)       { ebp = eb0; off = 0; }
        else if (t < 192) { ebp = eb1; off = 64; }
        else if (t < 320) { ebp = eb2; off = 192; }
        else              { ebp = eb3; off = 320; }
        int local = t - off;
        int mt = local >> 5, q = local & 31;
        int hi2 = q >> 4, reg = q & 15;
        int row = (reg & 3) + 8 * (reg >> 2) + 4 * hi2;
        sbR[t] = ebp[mt * 32 + row];
    }

    // wave-private zero + stage of this wave's patch
    unsigned short* Aw = A[w];
    {
        u32x4 z = {0u, 0u, 0u, 0u};
        for (int t = l; t < 300; t += 64) ((u32x4*)Aw)[t] = z;   // FULL 2400 u16
        for (int t = l; t < 192; t += 64) {
            int cin = t >> 6, pix = t & 63, i = pix >> 3, j = pix & 7;
            float v = X[((size_t)(b * 3 + cin) * 128 + (py * 8 + i)) * 128 + (px * 8 + j)];
            Aw[(1 + i) * ROWS + (1 + j) * CP + cin] = f2h_bits(v);
        }
    }
    __syncthreads();   // sbR/se visibility; A is wave-private

    int l31 = l & 31, hi = l >> 5;
    float* pout = psums + (size_t)(b * 256 + p) * 32;

    layer32<3, 4, 2, 8, false>(Aw, wA0, sbR,       se[0][w], l, hi, l31, nullptr);
    layer32<5, 8, 4, 16, false>(Aw, wA1, sbR + 64,  se[1][w], l, hi, l31, nullptr);
    layer32<9, 16, 4, 16, false>(Aw, wA2, sbR + 192, se[2][w], l, hi, l31, nullptr);
    layer32<9, 16, 8, 32, true>(Aw, wA3, sbR + 320, se[3][w], l, hi, l31, pout);
}

// ---------------- FC: 256 blocks = 16 b x 16 class-chunks -------------------
__global__ __launch_bounds__(256) void fc_kernel(
    const float* __restrict__ psums, const float* __restrict__ fcw,
    const float* __restrict__ fcb, float* __restrict__ out)
{
    int b = blockIdx.x >> 4, chunk = blockIdx.x & 15;
    __shared__ float pooled[2048];
    for (int t = threadIdx.x; t < 2048; t += 256) {
        int c = t >> 6, cell = t & 63, oy = cell >> 3, ox = cell & 7;
        float s = 0.0f;
        #pragma unroll
        for (int dy = 0; dy < 2; ++dy)
            #pragma unroll
            for (int dx = 0; dx < 2; ++dx) {
                int pp = (2 * oy + dy) * 16 + (2 * ox + dx);
                s += psums[(size_t)(b * 256 + pp) * 32 + c];
            }
        pooled[t] = s * (1.0f / 256.0f);
    }
    __syncthreads();

    int wave = threadIdx.x >> 6, lane = threadIdx.x & 63;
    for (int ci = wave; ci < 7; ci += 4) {
        int cls = chunk * 7 + ci;
        if (cls < 100) {
            float a = 0.0f;
            #pragma unroll
            for (int r = 0; r < 32; ++r)
                a += pooled[r * 64 + lane] * fcw[(size_t)cls * 2048 + r * 64 + lane];
            #pragma unroll
            for (int off = 32; off > 0; off >>= 1) a += __shfl_down(a, off);
            if (lane == 0) out[b * 100 + cls] = a + fcb[cls];
        }
    }
}

// ---------------- Launch ----------------------------------------------------
extern "C" void kernel_launch(void* const* d_in, const int* in_sizes, int n_in,
                              void* d_out, int out_size, void* d_ws, size_t ws_size,
                              hipStream_t stream) {
    const float* X = (const float*)d_in[0];
    const float* eb[4];
    SetupArgs sa;
    for (int l = 0; l < 4; ++l) {
        sa.ew[l]  = (const float*)d_in[1 + 6*l + 0];
        eb[l]     = (const float*)d_in[1 + 6*l + 1];
        sa.rw[l]  = (const float*)d_in[1 + 6*l + 2];
        sa.rb[l]  = (const float*)d_in[1 + 6*l + 3];
        sa.rlw[l] = (const float*)d_in[1 + 6*l + 4];
        sa.rlb[l] = (const float*)d_in[1 + 6*l + 5];
    }
    const float* fcw = (const float*)d_in[25];
    const float* fcb = (const float*)d_in[26];

    char* ws = (char*)d_ws;
    float* probs  = (float*)ws;                       // 32 KB
    float* psums  = (float*)(ws + 32768);             // 512 KB
    unsigned short* wA0 = (unsigned short*)(ws + 32768 + 524288);
    unsigned short* wA1 = wA0 + 3072;                 // L0: 2 mt x 3 ks x 512
    unsigned short* wA2 = wA1 + 10240;                // L1: 4 x 5 x 512
    unsigned short* wA3 = wA2 + 18432;                // L2: 4 x 9 x 512
    // L3: 8 x 9 x 512 = 36864 halves

    sa.probs = probs; sa.w0 = wA0; sa.w1 = wA1; sa.w2 = wA2; sa.w3 = wA3;

    setup_all<<<524, 256, 0, stream>>>(sa);
    pce_fused<<<1024, 256, 0, stream>>>(X, wA0, wA1, wA2, wA3,
                                        eb[0], eb[1], eb[2], eb[3], probs, psums);
    fc_kernel<<<256, 256, 0, stream>>>(psums, fcw, fcb, (float*)d_out);
}

// Round 23
// 64.381 us; speedup vs baseline: 1.0077x; 1.0077x over previous
//
#include <hip/hip_runtime.h>
#include <math.h>

#define NE 8
#define PI_F 3.14159265358979323846f

typedef _Float16 half8 __attribute__((ext_vector_type(8)));
typedef float f32x4 __attribute__((ext_vector_type(4)));
typedef float f32x16 __attribute__((ext_vector_type(16)));
typedef unsigned int uint2v __attribute__((ext_vector_type(2)));
typedef unsigned int u32x4 __attribute__((ext_vector_type(4)));
typedef unsigned short u16x4 __attribute__((ext_vector_type(4)));

// Activation LDS layout: fp16, [y 0..9][x 0..9][c 0..23(pad)], u16 units
#define CP 24
#define ROWS 240        // 10 * CP
#define NELEM 2400      // 10*10*CP u16

__device__ __forceinline__ unsigned short f2h_bits(float v) {
    union { _Float16 h; unsigned short u; } cv;
    cv.h = (_Float16)v;
    return cv.u;
}

// ---------------- Setup: routers (blocks 0..255) + weight prep --------------
struct SetupArgs {
    const float* rw[4]; const float* rb[4]; const float* rlw[4]; const float* rlb[4];
    const float* ew[4];
    float* probs;
    unsigned short* w0; unsigned short* w1; unsigned short* w2; unsigned short* w3;
};

// 32x32x16 A-fragment prep. k = r*CSTR + cin. m indexes ew rows directly.
// Fragment (mt,ks,lane,j): m = mt*32 + (lane&31), k = ks*16 + (lane>>5)*8 + j.
template<int CIN, int CSTR, int KSL>
__device__ __forceinline__ void prep_one32(
    const float* __restrict__ ew, unsigned short* __restrict__ wA, int idx)
{
    int j    = idx & 7;
    int lane = (idx >> 3) & 63;
    int t2   = idx >> 9;
    int ks   = t2 % KSL;
    int mt   = t2 / KSL;
    int m    = mt * 32 + (lane & 31);
    int k    = ks * 16 + (lane >> 5) * 8 + j;
    int cin  = k % CSTR, r = k / CSTR;
    float val = 0.0f;
    if (cin < CIN && r < 9)
        val = ew[((size_t)m * CIN + cin) * 9 + r];
    wA[idx] = f2h_bits(val);
}

__global__ __launch_bounds__(256) void setup_all(SetupArgs sa)
{
    int bx = blockIdx.x, tid = threadIdx.x;
    if (bx < 256) {
        int layer = tid >> 6, lane = tid & 63;
        const float* rw  = sa.rw[layer];  const float* rb  = sa.rb[layer];
        const float* rlw = sa.rlw[layer]; const float* rlb = sa.rlb[layer];
        int p = bx, py = p >> 4, px = p & 15;
        int i = lane >> 3, j = lane & 7;
        int y = py * 8 + i, x = px * 8 + j;

        float base0 = (x + 0.5f) / 128.0f;
        float base1 = (y + 0.5f) / 128.0f;
        float base2 = (j + 0.5f) / 8.0f;
        float base3 = (i + 0.5f) / 8.0f;

        float coord[52];
        coord[0] = base0; coord[1] = base1; coord[2] = base2; coord[3] = base3;
        int c = 4;
        #pragma unroll
        for (int f = 0; f < 6; ++f) {
            float w = PI_F * (float)(1 << f);
            coord[c+0] = sinf(w * base0); coord[c+1] = sinf(w * base1);
            coord[c+2] = sinf(w * base2); coord[c+3] = sinf(w * base3);
            coord[c+4] = cosf(w * base0); coord[c+5] = cosf(w * base1);
            coord[c+6] = cosf(w * base2); coord[c+7] = cosf(w * base3);
            c += 8;
        }
        float z[16];
        #pragma unroll
        for (int r = 0; r < 16; ++r) {
            float a = rb[r];
            #pragma unroll
            for (int cc = 0; cc < 52; ++cc) a += rw[r*52 + cc] * coord[cc];
            z[r] = fmaxf(a, 0.0f);
        }
        #pragma unroll
        for (int r = 0; r < 16; ++r) {
            float v = z[r];
            #pragma unroll
            for (int off = 32; off > 0; off >>= 1) v += __shfl_xor(v, off);
            z[r] = v * (1.0f / 64.0f);
        }
        int e = lane & 7;
        float logit = rlb[e];
        #pragma unroll
        for (int r = 0; r < 16; ++r) logit += rlw[e*16 + r] * z[r];
        float m = logit;
        #pragma unroll
        for (int off = 4; off > 0; off >>= 1) m = fmaxf(m, __shfl_xor(m, off));
        float ex = expf(logit - m);
        float s = ex;
        #pragma unroll
        for (int off = 4; off > 0; off >>= 1) s += __shfl_xor(s, off);
        float pr = ex / s;
        pr = (pr >= 0.05f) ? pr : 0.0f;
        float s2 = pr;
        #pragma unroll
        for (int off = 4; off > 0; off >>= 1) s2 += __shfl_xor(s2, off);
        pr = pr / (s2 + 1e-9f);
        if (lane < 8) sa.probs[layer * 2048 + p * 8 + lane] = pr;
    } else {
        int idx = (bx - 256) * 256 + tid;
        if (idx < 3072)       prep_one32<3, 4, 3>(sa.ew[0], sa.w0, idx);
        else if (idx < 13312) prep_one32<8, 8, 5>(sa.ew[1], sa.w1, idx - 3072);
        else if (idx < 31744) prep_one32<16, 16, 9>(sa.ew[2], sa.w2, idx - 13312);
        else if (idx < 68608) prep_one32<16, 16, 9>(sa.ew[3], sa.w3, idx - 31744);
    }
}

// ---------------- B-fragment build: pixel n (0..63), channel-half hi --------
template<int KSL, int CSTR>
__device__ __forceinline__ void build_B32(
    half8* B, const unsigned short* ain, int n, int hi)
{
    int pr = n >> 3, pc = n & 7;
    int rbase = pr * ROWS + pc * CP;
    if (CSTR == 16) {
        #pragma unroll
        for (int ks = 0; ks < KSL; ++ks) {
            int off = ((ks / 3) * 10 + (ks % 3)) * CP + hi * 8;
            B[ks] = *(const half8*)(ain + rbase + off);
        }
    } else if (CSTR == 8) {
        #pragma unroll
        for (int ks = 0; ks < KSL; ++ks) {
            int r0 = 2 * ks, r1 = 2 * ks + 1;
            int o0 = ((r0 / 3) * 10 + (r0 % 3)) * CP;
            int o1 = (r1 < 9) ? ((r1 / 3) * 10 + (r1 % 3)) * CP : 0;
            int off = hi ? o1 : o0;
            half8 v{};
            if (2 * ks + hi < 9) v = *(const half8*)(ain + rbase + off);
            B[ks] = v;
        }
    } else { // CSTR == 4
        #pragma unroll
        for (int ks = 0; ks < KSL; ++ks) {
            union { half8 v; uint2v u2[2]; } bb;
            #pragma unroll
            for (int h = 0; h < 2; ++h) {
                int ra = 4 * ks + h;          // hi=0 taps
                int rb_ = 4 * ks + 2 + h;     // hi=1 taps
                int oa = (ra < 9) ? ((ra / 3) * 10 + (ra % 3)) * CP : 0;
                int ob = (rb_ < 9) ? ((rb_ / 3) * 10 + (rb_ % 3)) * CP : 0;
                int r = 4 * ks + 2 * hi + h;
                int off = hi ? ob : oa;
                uint2v u{};
                if (r < 9) u = *(const uint2v*)(ain + rbase + off);
                bb.u2[h] = u;
            }
            B[ks] = bb.v;
        }
    }
}

// ---------------- One layer, 32x32x16 MFMA, whole patch per wave ------------
// CPE = channels per expert (8, 16, 32). sbR_L = bias in C-reg order.
// s_setprio(1) wraps the MFMA cluster (T5, verified +17% in R20).
template<int KSL, int CSTR, int MT, int CPE, bool LAST>
__device__ __forceinline__ void layer32(
    unsigned short* Aw,
    const unsigned short* __restrict__ wA,
    const float* sbR_L, const float* se_L,
    int l, int hi, int l31, float* pout)
{
    int n0 = l31, n1 = 32 + l31;
    half8 B0[KSL], B1[KSL];
    build_B32<KSL, CSTR>(B0, Aw, n0, hi);
    build_B32<KSL, CSTR>(B1, Aw, n1, hi);

    constexpr int KH0 = (KSL + 1) / 2;
    constexpr int KH1 = KSL - KH0;

    f32x16 accL = {0.f};                         // CPE==32 (LAST)
    f32x4 acc0a = {0,0,0,0}, acc0b = {0,0,0,0};  // CPE==16 nt0
    f32x4 acc1a = {0,0,0,0}, acc1b = {0,0,0,0};  // CPE==16 nt1
    f32x4 acc0s = {0,0,0,0}, acc1s = {0,0,0,0};  // CPE==8

    const unsigned short* apl = wA + l * 8;
    half8 A0[KH0], A1[KH1 > 0 ? KH1 : 1];
    #pragma unroll
    for (int q = 0; q < KH0; ++q)
        A0[q] = *(const half8*)(apl + q * 512);

    #pragma unroll 1
    for (int mt = 0; mt < MT; ++mt) {
        const unsigned short* base = apl + mt * (KSL * 512);
        #pragma unroll
        for (int q = 0; q < KH1; ++q)
            A1[q] = *(const half8*)(base + (KH0 + q) * 512);

        const float* bp = sbR_L + mt * 32 + hi * 16;
        f32x4 b0 = *(const f32x4*)(bp);
        f32x4 b1 = *(const f32x4*)(bp + 4);
        f32x4 b2 = *(const f32x4*)(bp + 8);
        f32x4 b3 = *(const f32x4*)(bp + 12);
        f32x16 ct0;
        #pragma unroll
        for (int i = 0; i < 4; ++i) {
            ct0[i] = b0[i]; ct0[4+i] = b1[i]; ct0[8+i] = b2[i]; ct0[12+i] = b3[i];
        }
        f32x16 ct1 = ct0;

        __builtin_amdgcn_s_setprio(1);
        #pragma unroll
        for (int q = 0; q < KH0; ++q) {
            ct0 = __builtin_amdgcn_mfma_f32_32x32x16_f16(A0[q], B0[q], ct0, 0, 0, 0);
            ct1 = __builtin_amdgcn_mfma_f32_32x32x16_f16(A0[q], B1[q], ct1, 0, 0, 0);
        }

        const unsigned short* nbase = apl + ((mt + 1 < MT) ? (mt + 1) : 0) * (KSL * 512);
        #pragma unroll
        for (int q = 0; q < KH0; ++q)
            A0[q] = *(const half8*)(nbase + q * 512);

        #pragma unroll
        for (int q = 0; q < KH1; ++q) {
            ct0 = __builtin_amdgcn_mfma_f32_32x32x16_f16(A1[q], B0[KH0 + q], ct0, 0, 0, 0);
            ct1 = __builtin_amdgcn_mfma_f32_32x32x16_f16(A1[q], B1[KH0 + q], ct1, 0, 0, 0);
        }
        __builtin_amdgcn_s_setprio(0);

        if (CPE == 32) {
            float pe = se_L[mt];
            #pragma unroll
            for (int g = 0; g < 16; ++g)
                accL[g] = fmaf(fmaxf(ct0[g], 0.f) + fmaxf(ct1[g], 0.f), pe, accL[g]);
        } else if (CPE == 16) {
            float pe0 = se_L[2 * mt], pe1 = se_L[2 * mt + 1];
            #pragma unroll
            for (int g = 0; g < 4; ++g) {
                acc0a[g] = fmaf(fmaxf(ct0[g],      0.f), pe0, acc0a[g]);
                acc0a[g] = fmaf(fmaxf(ct0[8 + g],  0.f), pe1, acc0a[g]);
                acc0b[g] = fmaf(fmaxf(ct0[4 + g],  0.f), pe0, acc0b[g]);
                acc0b[g] = fmaf(fmaxf(ct0[12 + g], 0.f), pe1, acc0b[g]);
                acc1a[g] = fmaf(fmaxf(ct1[g],      0.f), pe0, acc1a[g]);
                acc1a[g] = fmaf(fmaxf(ct1[8 + g],  0.f), pe1, acc1a[g]);
                acc1b[g] = fmaf(fmaxf(ct1[4 + g],  0.f), pe0, acc1b[g]);
                acc1b[g] = fmaf(fmaxf(ct1[12 + g], 0.f), pe1, acc1b[g]);
            }
        } else { // CPE == 8
            #pragma unroll
            for (int q = 0; q < 4; ++q) {
                float pe = se_L[4 * mt + q];
                #pragma unroll
                for (int g = 0; g < 4; ++g) {
                    acc0s[g] = fmaf(fmaxf(ct0[4 * q + g], 0.f), pe, acc0s[g]);
                    acc1s[g] = fmaf(fmaxf(ct1[4 * q + g], 0.f), pe, acc1s[g]);
                }
            }
        }
    }

    if (!LAST) {
        int wb0 = (1 + (n0 >> 3)) * ROWS + (1 + (n0 & 7)) * CP;
        int wb1 = (1 + (n1 >> 3)) * ROWS + (1 + (n1 & 7)) * CP;
        union { _Float16 h[4]; u16x4 u; } o;
        if (CPE == 8) {
            #pragma unroll
            for (int g = 0; g < 4; ++g) o.h[g] = (_Float16)acc0s[g];
            *(u16x4*)(Aw + wb0 + 4 * hi) = o.u;
            #pragma unroll
            for (int g = 0; g < 4; ++g) o.h[g] = (_Float16)acc1s[g];
            *(u16x4*)(Aw + wb1 + 4 * hi) = o.u;
        } else { // CPE == 16
            #pragma unroll
            for (int g = 0; g < 4; ++g) o.h[g] = (_Float16)acc0a[g];
            *(u16x4*)(Aw + wb0 + 4 * hi) = o.u;
            #pragma unroll
            for (int g = 0; g < 4; ++g) o.h[g] = (_Float16)acc0b[g];
            *(u16x4*)(Aw + wb0 + 8 + 4 * hi) = o.u;
            #pragma unroll
            for (int g = 0; g < 4; ++g) o.h[g] = (_Float16)acc1a[g];
            *(u16x4*)(Aw + wb1 + 4 * hi) = o.u;
            #pragma unroll
            for (int g = 0; g < 4; ++g) o.h[g] = (_Float16)acc1b[g];
            *(u16x4*)(Aw + wb1 + 8 + 4 * hi) = o.u;
        }
    } else {
        // channel sums over 64 pixels: xor-reduce within 32-lane halves
        #pragma unroll
        for (int g = 0; g < 16; ++g) {
            float s = accL[g];
            s += __shfl_xor(s, 1);  s += __shfl_xor(s, 2);
            s += __shfl_xor(s, 4);  s += __shfl_xor(s, 8);
            s += __shfl_xor(s, 16);
            accL[g] = s;
        }
        if (l31 == 0) {
            #pragma unroll
            for (int qd = 0; qd < 4; ++qd) {
                f32x4 v = { accL[4*qd], accL[4*qd+1], accL[4*qd+2], accL[4*qd+3] };
                *(f32x4*)(pout + qd * 8 + 4 * hi) = v;
            }
        }
    }
}

// ---------------- Fused all-4-layer conv, 1 patch per wave, 32x32 MFMA ------
__global__ __launch_bounds__(256, 2) void pce_fused(
    const float* __restrict__ X,
    const unsigned short* __restrict__ wA0, const unsigned short* __restrict__ wA1,
    const unsigned short* __restrict__ wA2, const unsigned short* __restrict__ wA3,
    const float* __restrict__ eb0, const float* __restrict__ eb1,
    const float* __restrict__ eb2, const float* __restrict__ eb3,
    const float* __restrict__ probs,  // [4][256][8]
    float* __restrict__ psums)        // [16][256][32]
{
    int bx = blockIdx.x;              // 0..1023
    int b = bx >> 6;
    int pbase = (bx & 63) << 2;
    int tid = threadIdx.x;
    int w = tid >> 6, l = tid & 63;
    int p = pbase + w;
    int py = p >> 4, px = p & 15;

    __shared__ alignas(16) unsigned short A[4][NELEM];   // 19.2 KB
    __shared__ alignas(16) float sbR[576];               // bias, C-reg order
    __shared__ alignas(16) float se[4][4][8];            // [layer][wave][expert]

    if (tid < 128) {
        int layer = tid >> 5, q = (tid >> 3) & 3, e = tid & 7;
        se[layer][q][e] = probs[layer * 2048 + (pbase + q) * 8 + e];
    }
    // bias reorder: sbR[off + mt*32 + hi*16 + reg] = ebL[mt*32 + row(reg,hi)]
    for (int t = tid; t < 576; t += 256) {
        const float* ebp; int off;
        if (t < 64)       { ebp = eb0; off = 0; }
        else if (t < 192) { ebp = eb1; off = 64; }
        else if (t < 320) { ebp = eb2; off = 192; }
        else              { ebp = eb3; off = 320; }
        int local = t - off;
        int mt = local >> 5, q = local & 31;
        int hi2 = q >> 4, reg = q & 15;
        int row = (reg & 3) + 8 * (reg >> 2) + 4 * hi2;
        sbR[t] = ebp[mt * 32 + row];
    }

    // wave-private zero + stage of this wave's patch
    unsigned short* Aw = A[w];
    {
        u32x4 z = {0u, 0u, 0u, 0u};
        for (int t = l; t < 300; t += 64) ((u32x4*)Aw)[t] = z;   // FULL 2400 u16
        for (int t = l; t < 192; t += 64) {
            int cin = t >> 6, pix = t & 63, i = pix >> 3, j = pix & 7;
            float v = X[((size_t)(b * 3 + cin) * 128 + (py * 8 + i)) * 128 + (px * 8 + j)];
            Aw[(1 + i) * ROWS + (1 + j) * CP + cin] = f2h_bits(v);
        }
    }
    __syncthreads();   // sbR/se visibility; A is wave-private

    int l31 = l & 31, hi = l >> 5;
    float* pout = psums + (size_t)(b * 256 + p) * 32;

    layer32<3, 4, 2, 8, false>(Aw, wA0, sbR,       se[0][w], l, hi, l31, nullptr);
    layer32<5, 8, 4, 16, false>(Aw, wA1, sbR + 64,  se[1][w], l, hi, l31, nullptr);
    layer32<9, 16, 4, 16, false>(Aw, wA2, sbR + 192, se[2][w], l, hi, l31, nullptr);
    layer32<9, 16, 8, 32, true>(Aw, wA3, sbR + 320, se[3][w], l, hi, l31, pout);
}

// ---------------- FC: 128 blocks = 16 b x 8 class-chunks --------------------
__global__ __launch_bounds__(256) void fc_kernel(
    const float* __restrict__ psums, const float* __restrict__ fcw,
    const float* __restrict__ fcb, float* __restrict__ out)
{
    int b = blockIdx.x >> 3, chunk = blockIdx.x & 7;
    __shared__ float pooled[2048];
    for (int t = threadIdx.x; t < 2048; t += 256) {
        int c = t >> 6, cell = t & 63, oy = cell >> 3, ox = cell & 7;
        float s = 0.0f;
        #pragma unroll
        for (int dy = 0; dy < 2; ++dy)
            #pragma unroll
            for (int dx = 0; dx < 2; ++dx) {
                int pp = (2 * oy + dy) * 16 + (2 * ox + dx);
                s += psums[(size_t)(b * 256 + pp) * 32 + c];
            }
        pooled[t] = s * (1.0f / 256.0f);
    }
    __syncthreads();

    int wave = threadIdx.x >> 6, lane = threadIdx.x & 63;
    for (int ci = wave; ci < 13; ci += 4) {
        int cls = chunk * 13 + ci;
        if (cls < 100) {
            float a = 0.0f;
            #pragma unroll
            for (int r = 0; r < 32; ++r)
                a += pooled[r * 64 + lane] * fcw[(size_t)cls * 2048 + r * 64 + lane];
            #pragma unroll
            for (int off = 32; off > 0; off >>= 1) a += __shfl_down(a, off);
            if (lane == 0) out[b * 100 + cls] = a + fcb[cls];
        }
    }
}

// ---------------- Launch ----------------------------------------------------
extern "C" void kernel_launch(void* const* d_in, const int* in_sizes, int n_in,
                              void* d_out, int out_size, void* d_ws, size_t ws_size,
                              hipStream_t stream) {
    const float* X = (const float*)d_in[0];
    const float* eb[4];
    SetupArgs sa;
    for (int l = 0; l < 4; ++l) {
        sa.ew[l]  = (const float*)d_in[1 + 6*l + 0];
        eb[l]     = (const float*)d_in[1 + 6*l + 1];
        sa.rw[l]  = (const float*)d_in[1 + 6*l + 2];
        sa.rb[l]  = (const float*)d_in[1 + 6*l + 3];
        sa.rlw[l] = (const float*)d_in[1 + 6*l + 4];
        sa.rlb[l] = (const float*)d_in[1 + 6*l + 5];
    }
    const float* fcw = (const float*)d_in[25];
    const float* fcb = (const float*)d_in[26];

    char* ws = (char*)d_ws;
    float* probs  = (float*)ws;                       // 32 KB
    float* psums  = (float*)(ws + 32768);             // 512 KB
    unsigned short* wA0 = (unsigned short*)(ws + 32768 + 524288);
    unsigned short* wA1 = wA0 + 3072;                 // L0: 2 mt x 3 ks x 512
    unsigned short* wA2 = wA1 + 10240;                // L1: 4 x 5 x 512
    unsigned short* wA3 = wA2 + 18432;                // L2: 4 x 9 x 512
    // L3: 8 x 9 x 512 = 36864 halves

    sa.probs = probs; sa.w0 = wA0; sa.w1 = wA1; sa.w2 = wA2; sa.w3 = wA3;

    setup_all<<<524, 256, 0, stream>>>(sa);
    pce_fused<<<1024, 256, 0, stream>>>(X, wA0, wA1, wA2, wA3,
                                        eb[0], eb[1], eb[2], eb[3], probs, psums);
    fc_kernel<<<128, 256, 0, stream>>>(psums, fcw, fcb, (float*)d_out);
}